// Round 5
// baseline (240.681 us; speedup 1.0000x reference)
//
#include <hip/hip_runtime.h>
#include <stdint.h>

static constexpr int BLOCK = 256;
static constexpr int ITEMS = 8;
static constexpr int CHUNK = BLOCK * ITEMS;   // 2048 elements per block
static constexpr int MAXNB = 1024;            // 1024 * 2048 = 2097152 = N
static constexpr unsigned POISON32 = 0xAAAAAAAAu;

typedef float f4v __attribute__((ext_vector_type(4)));

#define GAMMA_F 0.99f
static __device__ __forceinline__ float gl_const() { return (float)(0.99 * 0.95); }

// affine compose: self ∘ right (right applied first): x -> a1*(a2*x+b2)+b1
__device__ __forceinline__ void compose(float& a1, float& b1, float a2, float b2) {
    b1 = fmaf(a1, b2, b1);
    a1 = a1 * a2;
}

// ---------------- bool dtype runtime probe ----------------
// 0 = int32, 1 = uint8/bool, 2 = float32. Byte pattern of first 1024 bytes.
__device__ __forceinline__ int detect_mode(const void* term, int n_elems, int* flg) {
    int t = threadIdx.x;
    if (t == 0) { flg[0] = 0; flg[1] = 0; }
    __syncthreads();
    if (t < 256) {
        const unsigned char* p = (const unsigned char*)term;
        int i0 = 4 * t;
        if (i0 + 3 < n_elems) {
            unsigned b1 = p[i0 + 1], b2 = p[i0 + 2], b3 = p[i0 + 3];
            if (b1) atomicOr(&flg[0], 1);
            if (b2 | b3) atomicOr(&flg[1], 1);
        }
    }
    __syncthreads();
    return flg[0] ? 1 : (flg[1] ? 2 : 0);
}

__device__ __forceinline__ int load_bool1(const void* p, long i, int mode) {
    if (mode == 1) return ((const unsigned char*)p)[i] != 0;
    if (mode == 0) return ((const int*)p)[i] != 0;
    return ((const float*)p)[i] != 0.0f;
}

__device__ __forceinline__ void load_bool8(const void* p, long base, int mode, int* f) {
    if (mode == 1) {
        uint2 q = *(const uint2*)((const unsigned char*)p + base);
        unsigned w[2] = {q.x, q.y};
#pragma unroll
        for (int j = 0; j < 8; ++j) f[j] = (int)((w[j >> 2] >> ((j & 3) * 8)) & 0xffu);
    } else if (mode == 0) {
        const int4* q = (const int4*)((const int*)p + base);
#pragma unroll
        for (int k = 0; k < 2; ++k) {
            int4 v = q[k];
            f[4*k] = v.x; f[4*k+1] = v.y; f[4*k+2] = v.z; f[4*k+3] = v.w;
        }
    } else {
        const float4* q = (const float4*)((const float*)p + base);
#pragma unroll
        for (int k = 0; k < 2; ++k) {
            float4 v = q[k];
            f[4*k] = v.x != 0.f; f[4*k+1] = v.y != 0.f; f[4*k+2] = v.z != 0.f; f[4*k+3] = v.w != 0.f;
        }
    }
}

// c[j] = not_done * gamma*lambda ; d[j] = r + gamma*not_term*nv - v
__device__ __forceinline__ void compute_cd(
    const float* __restrict__ rewards, const float* __restrict__ values,
    const float* __restrict__ next_values, const void* __restrict__ term,
    const void* __restrict__ trunc, int mode, long base, int n,
    float* c, float* d, float* v)
{
    const float GL = gl_const();
    if (base + ITEMS <= n) {
        float r[ITEMS], nv[ITEMS];
        const float4* r4 = (const float4*)(rewards + base);
        const float4* v4 = (const float4*)(values + base);
        const float4* n4 = (const float4*)(next_values + base);
#pragma unroll
        for (int k = 0; k < 2; ++k) {
            float4 a = r4[k]; r[4*k]=a.x; r[4*k+1]=a.y; r[4*k+2]=a.z; r[4*k+3]=a.w;
            float4 b = v4[k]; v[4*k]=b.x; v[4*k+1]=b.y; v[4*k+2]=b.z; v[4*k+3]=b.w;
            float4 q = n4[k]; nv[4*k]=q.x; nv[4*k+1]=q.y; nv[4*k+2]=q.z; nv[4*k+3]=q.w;
        }
        int tm[ITEMS], tr[ITEMS];
        load_bool8(term,  base, mode, tm);
        load_bool8(trunc, base, mode, tr);
#pragma unroll
        for (int j = 0; j < ITEMS; ++j) {
            float nt = tm[j] ? 0.f : 1.f;
            float nd = (tm[j] | tr[j]) ? 0.f : 1.f;
            d[j] = r[j] + GAMMA_F * nt * nv[j] - v[j];
            c[j] = nd * GL;
        }
    } else {
#pragma unroll
        for (int j = 0; j < ITEMS; ++j) {
            long i = base + j;
            if (i < (long)n) {
                int tm = load_bool1(term, i, mode);
                int tr = load_bool1(trunc, i, mode);
                float nt = tm ? 0.f : 1.f;
                float nd = (tm | tr) ? 0.f : 1.f;
                v[j] = values[i];
                d[j] = rewards[i] + GAMMA_F * nt * next_values[i] - v[j];
                c[j] = nd * GL;
            } else { c[j] = 1.f; d[j] = 0.f; v[j] = 0.f; }
        }
    }
}

// ---------------- K1: aggregates + per-thread entry maps + moments,
//                  last-arriving block performs the global scan + stats ----------------
__global__ __launch_bounds__(BLOCK) void k1_agg(
    const float* __restrict__ rewards, const float* __restrict__ values,
    const float* __restrict__ next_values, const void* __restrict__ term,
    const void* __restrict__ trunc, float2* __restrict__ blockAgg,
    float2* __restrict__ E2, float4* __restrict__ bs4, float* __restrict__ bs1,
    float* __restrict__ S, float* __restrict__ stats,
    unsigned* __restrict__ counter, int n, int nb)
{
    __shared__ int flg[2];
    __shared__ float wA[4], wB[4];
    __shared__ float red[4][5];
    __shared__ int isLast;
    __shared__ float sA[BLOCK], sB[BLOCK];
    __shared__ double dS[BLOCK], dS2[BLOCK];

    const int t = threadIdx.x;
    const int lane = t & 63, w = t >> 6;
    const int bid = blockIdx.x;
    const int mode = detect_mode(term, n, flg);
    const long base = (long)bid * CHUNK + (long)t * ITEMS;

    float c[ITEMS], d[ITEMS], v[ITEMS];
    compute_cd(rewards, values, next_values, term, trunc, mode, base, n, c, d, v);

    // thread-serial affine aggregate of this thread's 8 items
    float a = 1.f, b = 0.f;
#pragma unroll
    for (int j = ITEMS - 1; j >= 0; --j) { b = fmaf(c[j], b, d[j]); a *= c[j]; }

    // wave suffix-inclusive scan via shuffles: H_l = F_l ∘ F_{l+1} ∘ ... ∘ F_63
#pragma unroll
    for (int dd = 1; dd < 64; dd <<= 1) {
        float ra = __shfl_down(a, dd, 64);
        float rb = __shfl_down(b, dd, 64);
        if (lane + dd < 64) { b = fmaf(a, rb, b); a *= ra; }
    }
    if (lane == 0) { wA[w] = a; wB[w] = b; }   // wave aggregate A_w
    // within-wave exclusive entry E = H_{l+1} (identity at lane 63)
    float ea = __shfl_down(a, 1, 64);
    float eb = __shfl_down(b, 1, 64);
    if (lane == 63) { ea = 1.f; eb = 0.f; }
    __syncthreads();
    // compose with later-wave aggregates
    for (int ww = w + 1; ww < 4; ++ww) compose(ea, eb, wA[ww], wB[ww]);
    if (t == 0) {
        float Aa = wA[0], Ab = wB[0];
        for (int ww = 1; ww < 4; ++ww) compose(Aa, Ab, wA[ww], wB[ww]);
        blockAgg[bid] = make_float2(Aa, Ab);
    }
    // persist per-thread block-entry map for the finalize kernel
    E2[(long)bid * BLOCK + t] = make_float2(ea, eb);

    // symbolic replay: adv_j = p*x_b + q ; accumulate 5 moment scalars
    float p = ea, q = eb;
    float sP = 0.f, sQ = 0.f, sP2 = 0.f, sPQ = 0.f, sQ2 = 0.f;
#pragma unroll
    for (int j = ITEMS - 1; j >= 0; --j) {
        p = c[j] * p;
        q = fmaf(c[j], q, d[j]);
        if (base + j < (long)n) {
            sP += p; sQ += q; sP2 += p*p; sPQ += p*q; sQ2 += q*q;
        }
    }
#pragma unroll
    for (int dd = 32; dd > 0; dd >>= 1) {
        sP  += __shfl_down(sP,  dd, 64);
        sQ  += __shfl_down(sQ,  dd, 64);
        sP2 += __shfl_down(sP2, dd, 64);
        sPQ += __shfl_down(sPQ, dd, 64);
        sQ2 += __shfl_down(sQ2, dd, 64);
    }
    if (lane == 0) { red[w][0]=sP; red[w][1]=sQ; red[w][2]=sP2; red[w][3]=sPQ; red[w][4]=sQ2; }
    __syncthreads();
    if (t == 0) {
        float m0=0,m1=0,m2=0,m3=0,m4=0;
        for (int ww = 0; ww < 4; ++ww) { m0+=red[ww][0]; m1+=red[ww][1]; m2+=red[ww][2]; m3+=red[ww][3]; m4+=red[ww][4]; }
        bs4[bid] = make_float4(m0, m1, m2, m3);
        bs1[bid] = m4;
    }

    // ---- last-block election (handles 0xAA-poisoned or zeroed counter) ----
    __threadfence();
    if (t == 0) {
        atomicCAS(counter, POISON32, 0u);              // first atomic op converts poison
        unsigned ticket = atomicAdd(counter, 1u);
        isLast = (ticket == (unsigned)(nb - 1));
    }
    __syncthreads();
    if (!isLast) return;
    __threadfence();   // acquire: other blocks' blockAgg/bs writes now visible

    // ---- global suffix scan of nb aggregates + analytic stats (ex-K2) ----
    float la[4], lb[4];
#pragma unroll
    for (int j = 0; j < 4; ++j) {
        int i = 4 * t + j;
        if (i < nb) { float2 f = blockAgg[i]; la[j] = f.x; lb[j] = f.y; }
        else        { la[j] = 1.f; lb[j] = 0.f; }
    }
    float ga = 1.f, gb = 0.f;
#pragma unroll
    for (int j = 3; j >= 0; --j) { gb = fmaf(la[j], gb, lb[j]); ga *= la[j]; }
    sA[t] = ga; sB[t] = gb;
    __syncthreads();
    for (int dd = 1; dd < BLOCK; dd <<= 1) {
        float ra = 1.f, rb = 0.f;
        if (t + dd < BLOCK) { ra = sA[t + dd]; rb = sB[t + dd]; }
        __syncthreads();
        gb = fmaf(ga, rb, gb);
        ga *= ra;
        sA[t] = ga; sB[t] = gb;
        __syncthreads();
    }
    float x = (t + 1 < BLOCK) ? sB[t + 1] : 0.f;   // suffix value entering block 4t+3
    double ds = 0.0, ds2 = 0.0;
#pragma unroll
    for (int j = 3; j >= 0; --j) {
        int i = 4 * t + j;
        if (i < nb) {
            S[i] = x;
            float4 s4 = bs4[i];
            double xd = (double)x;
            ds  += (double)s4.x * xd + (double)s4.y;
            ds2 += (double)s4.z * xd * xd + 2.0 * (double)s4.w * xd + (double)bs1[i];
        }
        x = fmaf(la[j], x, lb[j]);
    }
    dS[t] = ds; dS2[t] = ds2;
    __syncthreads();
    for (int dd = BLOCK / 2; dd > 0; dd >>= 1) {
        if (t < dd) { dS[t] += dS[t + dd]; dS2[t] += dS2[t + dd]; }
        __syncthreads();
    }
    if (t == 0) {
        double sum = dS[0], sumsq = dS2[0];
        double mean = sum / (double)n;
        double var = (sumsq - sum * sum / (double)n) / (double)(n - 1);
        if (var < 0.0) var = 0.0;
        stats[0] = (float)mean;
        stats[1] = 1.0f / ((float)sqrt(var) + 1e-9f);
    }
}

// ---------------- K3: pure streaming finalize (no LDS scan, no barriers) ----------------
__global__ __launch_bounds__(BLOCK) void k3_final(
    const float* __restrict__ rewards, const float* __restrict__ values,
    const float* __restrict__ next_values, const void* __restrict__ term,
    const void* __restrict__ trunc, const float* __restrict__ lp,
    const float* __restrict__ olp, const float2* __restrict__ E2,
    const float* __restrict__ S, const float* __restrict__ stats,
    float* __restrict__ out, int n)
{
    __shared__ int flg[2];
    const int t = threadIdx.x;
    const int bid = blockIdx.x;
    const int mode = detect_mode(term, n, flg);
    const long base = (long)bid * CHUNK + (long)t * ITEMS;

    float c[ITEMS], d[ITEMS], v[ITEMS];
    compute_cd(rewards, values, next_values, term, trunc, mode, base, n, c, d, v);

    float2 e = E2[(long)bid * BLOCK + t];
    float x = fmaf(e.x, S[bid], e.y);
    float adv[ITEMS];
#pragma unroll
    for (int j = ITEMS - 1; j >= 0; --j) {
        x = fmaf(c[j], x, d[j]);
        adv[j] = x;
    }
    const float mean = stats[0];
    const float inv  = stats[1];
    if (base + ITEMS <= n) {
        float l[ITEMS], o[ITEMS];
        const float4* l4 = (const float4*)(lp + base);
        const float4* o4 = (const float4*)(olp + base);
#pragma unroll
        for (int k = 0; k < 2; ++k) {
            float4 q = l4[k]; l[4*k]=q.x; l[4*k+1]=q.y; l[4*k+2]=q.z; l[4*k+3]=q.w;
            float4 w = o4[k]; o[4*k]=w.x; o[4*k+1]=w.y; o[4*k+2]=w.z; o[4*k+3]=w.w;
        }
        float buf[3 * ITEMS];
#pragma unroll
        for (int j = 0; j < ITEMS; ++j) {
            float an = (adv[j] - mean) * inv;
            float ratio = expf(l[j] - o[j]);
            float cl = fminf(fmaxf(ratio, 0.8f), 1.2f);
            buf[3*j]     = an;
            buf[3*j + 1] = adv[j] + v[j];
            buf[3*j + 2] = -fminf(ratio * an, cl * an);
        }
        f4v* dst = (f4v*)(out + 3 * base);   // 3*base % 4 == 0 → 16B aligned
#pragma unroll
        for (int k = 0; k < 6; ++k) {
            f4v val = { buf[4*k], buf[4*k+1], buf[4*k+2], buf[4*k+3] };
            __builtin_nontemporal_store(val, dst + k);   // out is write-once
        }
    } else {
        for (int j = 0; j < ITEMS; ++j) {
            long i = base + j;
            if (i < (long)n) {
                float an = (adv[j] - mean) * inv;
                float ratio = expf(lp[i] - olp[i]);
                float cl = fminf(fmaxf(ratio, 0.8f), 1.2f);
                out[3*i]     = an;
                out[3*i + 1] = adv[j] + v[j];
                out[3*i + 2] = -fminf(ratio * an, cl * an);
            }
        }
    }
}

extern "C" void kernel_launch(void* const* d_in, const int* in_sizes, int n_in,
                              void* d_out, int out_size, void* d_ws, size_t ws_size,
                              hipStream_t stream) {
    const float* rewards     = (const float*)d_in[0];
    const float* values      = (const float*)d_in[1];
    const float* next_values = (const float*)d_in[2];
    const float* lp          = (const float*)d_in[3];
    const float* olp         = (const float*)d_in[4];
    const void*  term        = d_in[5];
    const void*  trunc       = d_in[6];
    float* out = (float*)d_out;
    int n = in_sizes[0];
    int nb = (n + CHUNK - 1) / CHUNK;   // 1024 for N=2^21; must be <= MAXNB

    char* ws = (char*)d_ws;
    float2*   blockAgg = (float2*)ws;                                   // 8 KB
    float4*   bs4      = (float4*)(ws + MAXNB * 8);                     // 16 KB
    float*    bs1      = (float*) (ws + MAXNB * 8 + MAXNB * 16);        // 4 KB
    float*    S        = (float*) (ws + MAXNB * 8 + MAXNB * 16 + MAXNB * 4);
    float*    stats    = (float*) (ws + MAXNB * 8 + MAXNB * 16 + MAXNB * 8);
    unsigned* counter  = (unsigned*)(ws + MAXNB * 8 + MAXNB * 16 + MAXNB * 8 + 64);
    float2*   E2       = (float2*)(ws + MAXNB * 8 + MAXNB * 16 + MAXNB * 8 + 256); // 2 MB

    k1_agg <<<nb, BLOCK, 0, stream>>>(rewards, values, next_values, term, trunc,
                                      blockAgg, E2, bs4, bs1, S, stats, counter, n, nb);
    k3_final<<<nb, BLOCK, 0, stream>>>(rewards, values, next_values, term, trunc,
                                       lp, olp, E2, S, stats, out, n);
}

// Round 6
// 148.001 us; speedup vs baseline: 1.6262x; 1.6262x over previous
//
#include <hip/hip_runtime.h>
#include <stdint.h>

static constexpr int BLOCK = 256;
static constexpr int ITEMS = 8;
static constexpr int CHUNK = BLOCK * ITEMS;   // 2048 elements per block
static constexpr int MAXNB = 1024;            // 1024 * 2048 = 2097152 = N

typedef float f4v __attribute__((ext_vector_type(4)));

#define GAMMA_F 0.99f
static __device__ __forceinline__ float gl_const() { return (float)(0.99 * 0.95); }

// affine compose: self ∘ right (right applied first): x -> a1*(a2*x+b2)+b1
__device__ __forceinline__ void compose(float& a1, float& b1, float a2, float b2) {
    b1 = fmaf(a1, b2, b1);
    a1 = a1 * a2;
}

// ---------------- bool dtype runtime probe ----------------
// 0 = int32, 1 = uint8/bool, 2 = float32. Byte pattern of first 1024 bytes.
__device__ __forceinline__ int detect_mode(const void* term, int n_elems, int* flg) {
    int t = threadIdx.x;
    if (t == 0) { flg[0] = 0; flg[1] = 0; }
    __syncthreads();
    if (t < 256) {
        const unsigned char* p = (const unsigned char*)term;
        int i0 = 4 * t;
        if (i0 + 3 < n_elems) {
            unsigned b1 = p[i0 + 1], b2 = p[i0 + 2], b3 = p[i0 + 3];
            if (b1) atomicOr(&flg[0], 1);
            if (b2 | b3) atomicOr(&flg[1], 1);
        }
    }
    __syncthreads();
    return flg[0] ? 1 : (flg[1] ? 2 : 0);
}

__device__ __forceinline__ int load_bool1(const void* p, long i, int mode) {
    if (mode == 1) return ((const unsigned char*)p)[i] != 0;
    if (mode == 0) return ((const int*)p)[i] != 0;
    return ((const float*)p)[i] != 0.0f;
}

__device__ __forceinline__ void load_bool8(const void* p, long base, int mode, int* f) {
    if (mode == 1) {
        uint2 q = *(const uint2*)((const unsigned char*)p + base);
        unsigned w[2] = {q.x, q.y};
#pragma unroll
        for (int j = 0; j < 8; ++j) f[j] = (int)((w[j >> 2] >> ((j & 3) * 8)) & 0xffu);
    } else if (mode == 0) {
        const int4* q = (const int4*)((const int*)p + base);
#pragma unroll
        for (int k = 0; k < 2; ++k) {
            int4 v = q[k];
            f[4*k] = v.x; f[4*k+1] = v.y; f[4*k+2] = v.z; f[4*k+3] = v.w;
        }
    } else {
        const float4* q = (const float4*)((const float*)p + base);
#pragma unroll
        for (int k = 0; k < 2; ++k) {
            float4 v = q[k];
            f[4*k] = v.x != 0.f; f[4*k+1] = v.y != 0.f; f[4*k+2] = v.z != 0.f; f[4*k+3] = v.w != 0.f;
        }
    }
}

// c[j] = not_done * gamma*lambda ; d[j] = r + gamma*not_term*nv - v
__device__ __forceinline__ void compute_cd(
    const float* __restrict__ rewards, const float* __restrict__ values,
    const float* __restrict__ next_values, const void* __restrict__ term,
    const void* __restrict__ trunc, int mode, long base, int n,
    float* c, float* d, float* v)
{
    const float GL = gl_const();
    if (base + ITEMS <= n) {
        float r[ITEMS], nv[ITEMS];
        const float4* r4 = (const float4*)(rewards + base);
        const float4* v4 = (const float4*)(values + base);
        const float4* n4 = (const float4*)(next_values + base);
#pragma unroll
        for (int k = 0; k < 2; ++k) {
            float4 a = r4[k]; r[4*k]=a.x; r[4*k+1]=a.y; r[4*k+2]=a.z; r[4*k+3]=a.w;
            float4 b = v4[k]; v[4*k]=b.x; v[4*k+1]=b.y; v[4*k+2]=b.z; v[4*k+3]=b.w;
            float4 q = n4[k]; nv[4*k]=q.x; nv[4*k+1]=q.y; nv[4*k+2]=q.z; nv[4*k+3]=q.w;
        }
        int tm[ITEMS], tr[ITEMS];
        load_bool8(term,  base, mode, tm);
        load_bool8(trunc, base, mode, tr);
#pragma unroll
        for (int j = 0; j < ITEMS; ++j) {
            float nt = tm[j] ? 0.f : 1.f;
            float nd = (tm[j] | tr[j]) ? 0.f : 1.f;
            d[j] = r[j] + GAMMA_F * nt * nv[j] - v[j];
            c[j] = nd * GL;
        }
    } else {
#pragma unroll
        for (int j = 0; j < ITEMS; ++j) {
            long i = base + j;
            if (i < (long)n) {
                int tm = load_bool1(term, i, mode);
                int tr = load_bool1(trunc, i, mode);
                float nt = tm ? 0.f : 1.f;
                float nd = (tm | tr) ? 0.f : 1.f;
                v[j] = values[i];
                d[j] = rewards[i] + GAMMA_F * nt * next_values[i] - v[j];
                c[j] = nd * GL;
            } else { c[j] = 1.f; d[j] = 0.f; v[j] = 0.f; }
        }
    }
}

// ---------------- K1: shuffle-scan aggregates + entry maps + moment scalars ----
// NO device atomics / elections (round-5 lesson: ~1000 serialized same-address
// device atomics ≈ 100 µs on MI355X — a separate 2 µs launch is 50x cheaper).
__global__ __launch_bounds__(BLOCK) void k1_agg(
    const float* __restrict__ rewards, const float* __restrict__ values,
    const float* __restrict__ next_values, const void* __restrict__ term,
    const void* __restrict__ trunc, float2* __restrict__ blockAgg,
    float2* __restrict__ E2, float4* __restrict__ bs4, float* __restrict__ bs1,
    int n)
{
    __shared__ int flg[2];
    __shared__ float wA[4], wB[4];
    __shared__ float red[4][5];

    const int t = threadIdx.x;
    const int lane = t & 63, w = t >> 6;
    const int bid = blockIdx.x;
    const int mode = detect_mode(term, n, flg);
    const long base = (long)bid * CHUNK + (long)t * ITEMS;

    float c[ITEMS], d[ITEMS], v[ITEMS];
    compute_cd(rewards, values, next_values, term, trunc, mode, base, n, c, d, v);

    // thread-serial affine aggregate of this thread's 8 items
    float a = 1.f, b = 0.f;
#pragma unroll
    for (int j = ITEMS - 1; j >= 0; --j) { b = fmaf(c[j], b, d[j]); a *= c[j]; }

    // wave suffix-inclusive scan via shuffles: H_l = F_l ∘ ... ∘ F_63
#pragma unroll
    for (int dd = 1; dd < 64; dd <<= 1) {
        float ra = __shfl_down(a, dd, 64);
        float rb = __shfl_down(b, dd, 64);
        if (lane + dd < 64) { b = fmaf(a, rb, b); a *= ra; }
    }
    if (lane == 0) { wA[w] = a; wB[w] = b; }   // wave aggregate
    // within-wave exclusive entry E = H_{l+1} (identity at lane 63)
    float ea = __shfl_down(a, 1, 64);
    float eb = __shfl_down(b, 1, 64);
    if (lane == 63) { ea = 1.f; eb = 0.f; }
    __syncthreads();
    // compose with later-wave aggregates
    for (int ww = w + 1; ww < 4; ++ww) compose(ea, eb, wA[ww], wB[ww]);
    if (t == 0) {
        float Aa = wA[0], Ab = wB[0];
        for (int ww = 1; ww < 4; ++ww) compose(Aa, Ab, wA[ww], wB[ww]);
        blockAgg[bid] = make_float2(Aa, Ab);
    }
    // persist per-thread block-entry map for the finalize kernel
    E2[(long)bid * BLOCK + t] = make_float2(ea, eb);

    // symbolic replay: adv_j = p*x_b + q ; accumulate 5 moment scalars
    float p = ea, q = eb;
    float sP = 0.f, sQ = 0.f, sP2 = 0.f, sPQ = 0.f, sQ2 = 0.f;
#pragma unroll
    for (int j = ITEMS - 1; j >= 0; --j) {
        p = c[j] * p;
        q = fmaf(c[j], q, d[j]);
        if (base + j < (long)n) {
            sP += p; sQ += q; sP2 += p*p; sPQ += p*q; sQ2 += q*q;
        }
    }
#pragma unroll
    for (int dd = 32; dd > 0; dd >>= 1) {
        sP  += __shfl_down(sP,  dd, 64);
        sQ  += __shfl_down(sQ,  dd, 64);
        sP2 += __shfl_down(sP2, dd, 64);
        sPQ += __shfl_down(sPQ, dd, 64);
        sQ2 += __shfl_down(sQ2, dd, 64);
    }
    if (lane == 0) { red[w][0]=sP; red[w][1]=sQ; red[w][2]=sP2; red[w][3]=sPQ; red[w][4]=sQ2; }
    __syncthreads();
    if (t == 0) {
        float m0=0,m1=0,m2=0,m3=0,m4=0;
        for (int ww = 0; ww < 4; ++ww) { m0+=red[ww][0]; m1+=red[ww][1]; m2+=red[ww][2]; m3+=red[ww][3]; m4+=red[ww][4]; }
        bs4[bid] = make_float4(m0, m1, m2, m3);
        bs1[bid] = m4;
    }
}

// ---------------- K2: suffix scan of aggregates + analytic stats ----------------
__global__ __launch_bounds__(BLOCK) void k2_scan(
    const float2* __restrict__ blockAgg, const float4* __restrict__ bs4,
    const float* __restrict__ bs1, float* __restrict__ S,
    float* __restrict__ stats, int nb, int n)
{
    __shared__ float sA[BLOCK], sB[BLOCK];
    __shared__ double dS[BLOCK], dS2[BLOCK];
    const int t = threadIdx.x;
    float la[4], lb[4];
#pragma unroll
    for (int j = 0; j < 4; ++j) {
        int i = 4 * t + j;
        if (i < nb) { float2 f = blockAgg[i]; la[j] = f.x; lb[j] = f.y; }
        else        { la[j] = 1.f; lb[j] = 0.f; }
    }
    float a = 1.f, b = 0.f;
#pragma unroll
    for (int j = 3; j >= 0; --j) { b = fmaf(la[j], b, lb[j]); a *= la[j]; }
    sA[t] = a; sB[t] = b;
    __syncthreads();
    for (int dd = 1; dd < BLOCK; dd <<= 1) {
        float ra = 1.f, rb = 0.f;
        if (t + dd < BLOCK) { ra = sA[t + dd]; rb = sB[t + dd]; }
        __syncthreads();
        b = fmaf(a, rb, b);
        a *= ra;
        sA[t] = a; sB[t] = b;
        __syncthreads();
    }
    float x = (t + 1 < BLOCK) ? sB[t + 1] : 0.f;   // suffix value entering block 4t+3
    double ds = 0.0, ds2 = 0.0;
#pragma unroll
    for (int j = 3; j >= 0; --j) {
        int i = 4 * t + j;
        if (i < nb) {
            S[i] = x;
            float4 s4 = bs4[i];
            double xd = (double)x;
            ds  += (double)s4.x * xd + (double)s4.y;
            ds2 += (double)s4.z * xd * xd + 2.0 * (double)s4.w * xd + (double)bs1[i];
        }
        x = fmaf(la[j], x, lb[j]);
    }
    dS[t] = ds; dS2[t] = ds2;
    __syncthreads();
    for (int dd = BLOCK / 2; dd > 0; dd >>= 1) {
        if (t < dd) { dS[t] += dS[t + dd]; dS2[t] += dS2[t + dd]; }
        __syncthreads();
    }
    if (t == 0) {
        double sum = dS[0], sumsq = dS2[0];
        double mean = sum / (double)n;
        double var = (sumsq - sum * sum / (double)n) / (double)(n - 1);
        if (var < 0.0) var = 0.0;
        stats[0] = (float)mean;
        stats[1] = 1.0f / ((float)sqrt(var) + 1e-9f);
    }
}

// ---------------- K3: pure streaming finalize (no LDS scan, no barriers) ----------------
__global__ __launch_bounds__(BLOCK) void k3_final(
    const float* __restrict__ rewards, const float* __restrict__ values,
    const float* __restrict__ next_values, const void* __restrict__ term,
    const void* __restrict__ trunc, const float* __restrict__ lp,
    const float* __restrict__ olp, const float2* __restrict__ E2,
    const float* __restrict__ S, const float* __restrict__ stats,
    float* __restrict__ out, int n)
{
    __shared__ int flg[2];
    const int t = threadIdx.x;
    const int bid = blockIdx.x;
    const int mode = detect_mode(term, n, flg);
    const long base = (long)bid * CHUNK + (long)t * ITEMS;

    float c[ITEMS], d[ITEMS], v[ITEMS];
    compute_cd(rewards, values, next_values, term, trunc, mode, base, n, c, d, v);

    float2 e = E2[(long)bid * BLOCK + t];
    float x = fmaf(e.x, S[bid], e.y);
    float adv[ITEMS];
#pragma unroll
    for (int j = ITEMS - 1; j >= 0; --j) {
        x = fmaf(c[j], x, d[j]);
        adv[j] = x;
    }
    const float mean = stats[0];
    const float inv  = stats[1];
    if (base + ITEMS <= n) {
        float l[ITEMS], o[ITEMS];
        const float4* l4 = (const float4*)(lp + base);
        const float4* o4 = (const float4*)(olp + base);
#pragma unroll
        for (int k = 0; k < 2; ++k) {
            float4 q = l4[k]; l[4*k]=q.x; l[4*k+1]=q.y; l[4*k+2]=q.z; l[4*k+3]=q.w;
            float4 w = o4[k]; o[4*k]=w.x; o[4*k+1]=w.y; o[4*k+2]=w.z; o[4*k+3]=w.w;
        }
        float buf[3 * ITEMS];
#pragma unroll
        for (int j = 0; j < ITEMS; ++j) {
            float an = (adv[j] - mean) * inv;
            float ratio = expf(l[j] - o[j]);
            float cl = fminf(fmaxf(ratio, 0.8f), 1.2f);
            buf[3*j]     = an;
            buf[3*j + 1] = adv[j] + v[j];
            buf[3*j + 2] = -fminf(ratio * an, cl * an);
        }
        f4v* dst = (f4v*)(out + 3 * base);   // 3*base % 4 == 0 → 16B aligned
#pragma unroll
        for (int k = 0; k < 6; ++k) {
            f4v val = { buf[4*k], buf[4*k+1], buf[4*k+2], buf[4*k+3] };
            __builtin_nontemporal_store(val, dst + k);   // out is write-once
        }
    } else {
        for (int j = 0; j < ITEMS; ++j) {
            long i = base + j;
            if (i < (long)n) {
                float an = (adv[j] - mean) * inv;
                float ratio = expf(lp[i] - olp[i]);
                float cl = fminf(fmaxf(ratio, 0.8f), 1.2f);
                out[3*i]     = an;
                out[3*i + 1] = adv[j] + v[j];
                out[3*i + 2] = -fminf(ratio * an, cl * an);
            }
        }
    }
}

extern "C" void kernel_launch(void* const* d_in, const int* in_sizes, int n_in,
                              void* d_out, int out_size, void* d_ws, size_t ws_size,
                              hipStream_t stream) {
    const float* rewards     = (const float*)d_in[0];
    const float* values      = (const float*)d_in[1];
    const float* next_values = (const float*)d_in[2];
    const float* lp          = (const float*)d_in[3];
    const float* olp         = (const float*)d_in[4];
    const void*  term        = d_in[5];
    const void*  trunc       = d_in[6];
    float* out = (float*)d_out;
    int n = in_sizes[0];
    int nb = (n + CHUNK - 1) / CHUNK;   // 1024 for N=2^21; must be <= MAXNB

    char* ws = (char*)d_ws;
    float2* blockAgg = (float2*)ws;                                   // 8 KB
    float4* bs4      = (float4*)(ws + MAXNB * 8);                     // 16 KB
    float*  bs1      = (float*) (ws + MAXNB * 8 + MAXNB * 16);        // 4 KB
    float*  S        = (float*) (ws + MAXNB * 8 + MAXNB * 16 + MAXNB * 4);
    float*  stats    = (float*) (ws + MAXNB * 8 + MAXNB * 16 + MAXNB * 8);
    float2* E2       = (float2*)(ws + MAXNB * 8 + MAXNB * 16 + MAXNB * 8 + 256); // 2 MB

    k1_agg <<<nb, BLOCK, 0, stream>>>(rewards, values, next_values, term, trunc,
                                      blockAgg, E2, bs4, bs1, n);
    k2_scan<<<1,  BLOCK, 0, stream>>>(blockAgg, bs4, bs1, S, stats, nb, n);
    k3_final<<<nb, BLOCK, 0, stream>>>(rewards, values, next_values, term, trunc,
                                       lp, olp, E2, S, stats, out, n);
}

// Round 7
// 130.489 us; speedup vs baseline: 1.8445x; 1.1342x over previous
//
#include <hip/hip_runtime.h>
#include <stdint.h>

static constexpr int BLOCK = 256;
static constexpr int ITEMS = 8;
static constexpr int CHUNK = BLOCK * ITEMS;   // 2048 elements per block
static constexpr int MAXNB = 1024;            // 1024 * 2048 = 2097152 = N

#define GAMMA_F 0.99f
static __device__ __forceinline__ float gl_const() { return (float)(0.99 * 0.95); }

// affine compose: self ∘ right (right applied first): x -> a1*(a2*x+b2)+b1
__device__ __forceinline__ void compose(float& a1, float& b1, float a2, float b2) {
    b1 = fmaf(a1, b2, b1);
    a1 = a1 * a2;
}

// ---------------- bool dtype runtime probe ----------------
// 0 = int32, 1 = uint8/bool, 2 = float32. Byte pattern of first 1024 bytes.
__device__ __forceinline__ int detect_mode(const void* term, int n_elems, int* flg) {
    int t = threadIdx.x;
    if (t == 0) { flg[0] = 0; flg[1] = 0; }
    __syncthreads();
    if (t < 256) {
        const unsigned char* p = (const unsigned char*)term;
        int i0 = 4 * t;
        if (i0 + 3 < n_elems) {
            unsigned b1 = p[i0 + 1], b2 = p[i0 + 2], b3 = p[i0 + 3];
            if (b1) atomicOr(&flg[0], 1);
            if (b2 | b3) atomicOr(&flg[1], 1);
        }
    }
    __syncthreads();
    return flg[0] ? 1 : (flg[1] ? 2 : 0);
}

__device__ __forceinline__ int load_bool1(const void* p, long i, int mode) {
    if (mode == 1) return ((const unsigned char*)p)[i] != 0;
    if (mode == 0) return ((const int*)p)[i] != 0;
    return ((const float*)p)[i] != 0.0f;
}

__device__ __forceinline__ void load_bool8(const void* p, long base, int mode, int* f) {
    if (mode == 1) {
        uint2 q = *(const uint2*)((const unsigned char*)p + base);
        unsigned w[2] = {q.x, q.y};
#pragma unroll
        for (int j = 0; j < 8; ++j) f[j] = (int)((w[j >> 2] >> ((j & 3) * 8)) & 0xffu);
    } else if (mode == 0) {
        const int4* q = (const int4*)((const int*)p + base);
#pragma unroll
        for (int k = 0; k < 2; ++k) {
            int4 v = q[k];
            f[4*k] = v.x; f[4*k+1] = v.y; f[4*k+2] = v.z; f[4*k+3] = v.w;
        }
    } else {
        const float4* q = (const float4*)((const float*)p + base);
#pragma unroll
        for (int k = 0; k < 2; ++k) {
            float4 v = q[k];
            f[4*k] = v.x != 0.f; f[4*k+1] = v.y != 0.f; f[4*k+2] = v.z != 0.f; f[4*k+3] = v.w != 0.f;
        }
    }
}

// c[j] = not_done * gamma*lambda ; d[j] = r + gamma*not_term*nv - v
__device__ __forceinline__ void compute_cd(
    const float* __restrict__ rewards, const float* __restrict__ values,
    const float* __restrict__ next_values, const void* __restrict__ term,
    const void* __restrict__ trunc, int mode, long base, int n,
    float* c, float* d, float* v)
{
    const float GL = gl_const();
    if (base + ITEMS <= n) {
        float r[ITEMS], nv[ITEMS];
        const float4* r4 = (const float4*)(rewards + base);
        const float4* v4 = (const float4*)(values + base);
        const float4* n4 = (const float4*)(next_values + base);
#pragma unroll
        for (int k = 0; k < 2; ++k) {
            float4 a = r4[k]; r[4*k]=a.x; r[4*k+1]=a.y; r[4*k+2]=a.z; r[4*k+3]=a.w;
            float4 b = v4[k]; v[4*k]=b.x; v[4*k+1]=b.y; v[4*k+2]=b.z; v[4*k+3]=b.w;
            float4 q = n4[k]; nv[4*k]=q.x; nv[4*k+1]=q.y; nv[4*k+2]=q.z; nv[4*k+3]=q.w;
        }
        int tm[ITEMS], tr[ITEMS];
        load_bool8(term,  base, mode, tm);
        load_bool8(trunc, base, mode, tr);
#pragma unroll
        for (int j = 0; j < ITEMS; ++j) {
            float nt = tm[j] ? 0.f : 1.f;
            float nd = (tm[j] | tr[j]) ? 0.f : 1.f;
            d[j] = r[j] + GAMMA_F * nt * nv[j] - v[j];
            c[j] = nd * GL;
        }
    } else {
#pragma unroll
        for (int j = 0; j < ITEMS; ++j) {
            long i = base + j;
            if (i < (long)n) {
                int tm = load_bool1(term, i, mode);
                int tr = load_bool1(trunc, i, mode);
                float nt = tm ? 0.f : 1.f;
                float nd = (tm | tr) ? 0.f : 1.f;
                v[j] = values[i];
                d[j] = rewards[i] + GAMMA_F * nt * next_values[i] - v[j];
                c[j] = nd * GL;
            } else { c[j] = 1.f; d[j] = 0.f; v[j] = 0.f; }
        }
    }
}

// ---------------- K1: shuffle-scan aggregates + entry maps + moment scalars ----
// NO device atomics / elections (round-5 lesson: ~1000 serialized same-address
// device atomics ≈ 100 µs on MI355X — a separate 2 µs launch is 50x cheaper).
__global__ __launch_bounds__(BLOCK) void k1_agg(
    const float* __restrict__ rewards, const float* __restrict__ values,
    const float* __restrict__ next_values, const void* __restrict__ term,
    const void* __restrict__ trunc, float2* __restrict__ blockAgg,
    float2* __restrict__ E2, float4* __restrict__ bs4, float* __restrict__ bs1,
    int n)
{
    __shared__ int flg[2];
    __shared__ float wA[4], wB[4];
    __shared__ float red[4][5];

    const int t = threadIdx.x;
    const int lane = t & 63, w = t >> 6;
    const int bid = blockIdx.x;
    const int mode = detect_mode(term, n, flg);
    const long base = (long)bid * CHUNK + (long)t * ITEMS;

    float c[ITEMS], d[ITEMS], v[ITEMS];
    compute_cd(rewards, values, next_values, term, trunc, mode, base, n, c, d, v);

    // thread-serial affine aggregate of this thread's 8 items
    float a = 1.f, b = 0.f;
#pragma unroll
    for (int j = ITEMS - 1; j >= 0; --j) { b = fmaf(c[j], b, d[j]); a *= c[j]; }

    // wave suffix-inclusive scan via shuffles: H_l = F_l ∘ ... ∘ F_63
#pragma unroll
    for (int dd = 1; dd < 64; dd <<= 1) {
        float ra = __shfl_down(a, dd, 64);
        float rb = __shfl_down(b, dd, 64);
        if (lane + dd < 64) { b = fmaf(a, rb, b); a *= ra; }
    }
    if (lane == 0) { wA[w] = a; wB[w] = b; }   // wave aggregate
    // within-wave exclusive entry E = H_{l+1} (identity at lane 63)
    float ea = __shfl_down(a, 1, 64);
    float eb = __shfl_down(b, 1, 64);
    if (lane == 63) { ea = 1.f; eb = 0.f; }
    __syncthreads();
    // compose with later-wave aggregates
    for (int ww = w + 1; ww < 4; ++ww) compose(ea, eb, wA[ww], wB[ww]);
    if (t == 0) {
        float Aa = wA[0], Ab = wB[0];
        for (int ww = 1; ww < 4; ++ww) compose(Aa, Ab, wA[ww], wB[ww]);
        blockAgg[bid] = make_float2(Aa, Ab);
    }
    // persist per-thread block-entry map for the finalize kernel
    E2[(long)bid * BLOCK + t] = make_float2(ea, eb);

    // symbolic replay: adv_j = p*x_b + q ; accumulate 5 moment scalars
    float p = ea, q = eb;
    float sP = 0.f, sQ = 0.f, sP2 = 0.f, sPQ = 0.f, sQ2 = 0.f;
#pragma unroll
    for (int j = ITEMS - 1; j >= 0; --j) {
        p = c[j] * p;
        q = fmaf(c[j], q, d[j]);
        if (base + j < (long)n) {
            sP += p; sQ += q; sP2 += p*p; sPQ += p*q; sQ2 += q*q;
        }
    }
#pragma unroll
    for (int dd = 32; dd > 0; dd >>= 1) {
        sP  += __shfl_down(sP,  dd, 64);
        sQ  += __shfl_down(sQ,  dd, 64);
        sP2 += __shfl_down(sP2, dd, 64);
        sPQ += __shfl_down(sPQ, dd, 64);
        sQ2 += __shfl_down(sQ2, dd, 64);
    }
    if (lane == 0) { red[w][0]=sP; red[w][1]=sQ; red[w][2]=sP2; red[w][3]=sPQ; red[w][4]=sQ2; }
    __syncthreads();
    if (t == 0) {
        float m0=0,m1=0,m2=0,m3=0,m4=0;
        for (int ww = 0; ww < 4; ++ww) { m0+=red[ww][0]; m1+=red[ww][1]; m2+=red[ww][2]; m3+=red[ww][3]; m4+=red[ww][4]; }
        bs4[bid] = make_float4(m0, m1, m2, m3);
        bs1[bid] = m4;
    }
}

// ---------------- K2: suffix scan of aggregates + analytic stats ----------------
__global__ __launch_bounds__(BLOCK) void k2_scan(
    const float2* __restrict__ blockAgg, const float4* __restrict__ bs4,
    const float* __restrict__ bs1, float* __restrict__ S,
    float* __restrict__ stats, int nb, int n)
{
    __shared__ float sA[BLOCK], sB[BLOCK];
    __shared__ double dS[BLOCK], dS2[BLOCK];
    const int t = threadIdx.x;
    float la[4], lb[4];
#pragma unroll
    for (int j = 0; j < 4; ++j) {
        int i = 4 * t + j;
        if (i < nb) { float2 f = blockAgg[i]; la[j] = f.x; lb[j] = f.y; }
        else        { la[j] = 1.f; lb[j] = 0.f; }
    }
    float a = 1.f, b = 0.f;
#pragma unroll
    for (int j = 3; j >= 0; --j) { b = fmaf(la[j], b, lb[j]); a *= la[j]; }
    sA[t] = a; sB[t] = b;
    __syncthreads();
    for (int dd = 1; dd < BLOCK; dd <<= 1) {
        float ra = 1.f, rb = 0.f;
        if (t + dd < BLOCK) { ra = sA[t + dd]; rb = sB[t + dd]; }
        __syncthreads();
        b = fmaf(a, rb, b);
        a *= ra;
        sA[t] = a; sB[t] = b;
        __syncthreads();
    }
    float x = (t + 1 < BLOCK) ? sB[t + 1] : 0.f;   // suffix value entering block 4t+3
    double ds = 0.0, ds2 = 0.0;
#pragma unroll
    for (int j = 3; j >= 0; --j) {
        int i = 4 * t + j;
        if (i < nb) {
            S[i] = x;
            float4 s4 = bs4[i];
            double xd = (double)x;
            ds  += (double)s4.x * xd + (double)s4.y;
            ds2 += (double)s4.z * xd * xd + 2.0 * (double)s4.w * xd + (double)bs1[i];
        }
        x = fmaf(la[j], x, lb[j]);
    }
    dS[t] = ds; dS2[t] = ds2;
    __syncthreads();
    for (int dd = BLOCK / 2; dd > 0; dd >>= 1) {
        if (t < dd) { dS[t] += dS[t + dd]; dS2[t] += dS2[t + dd]; }
        __syncthreads();
    }
    if (t == 0) {
        double sum = dS[0], sumsq = dS2[0];
        double mean = sum / (double)n;
        double var = (sumsq - sum * sum / (double)n) / (double)(n - 1);
        if (var < 0.0) var = 0.0;
        stats[0] = (float)mean;
        stats[1] = 1.0f / ((float)sqrt(var) + 1e-9f);
    }
}

// ---------------- K3: pure streaming finalize (no LDS scan, no barriers) ----
// Plain float4 stores: round-6 lesson — nontemporal stores caused ~3x HBM
// write amplification (74 MB for a 24 MB output) via partial-line flushes.
__global__ __launch_bounds__(BLOCK) void k3_final(
    const float* __restrict__ rewards, const float* __restrict__ values,
    const float* __restrict__ next_values, const void* __restrict__ term,
    const void* __restrict__ trunc, const float* __restrict__ lp,
    const float* __restrict__ olp, const float2* __restrict__ E2,
    const float* __restrict__ S, const float* __restrict__ stats,
    float* __restrict__ out, int n)
{
    __shared__ int flg[2];
    const int t = threadIdx.x;
    const int bid = blockIdx.x;
    const int mode = detect_mode(term, n, flg);
    const long base = (long)bid * CHUNK + (long)t * ITEMS;

    float c[ITEMS], d[ITEMS], v[ITEMS];
    compute_cd(rewards, values, next_values, term, trunc, mode, base, n, c, d, v);

    float2 e = E2[(long)bid * BLOCK + t];
    float x = fmaf(e.x, S[bid], e.y);
    float adv[ITEMS];
#pragma unroll
    for (int j = ITEMS - 1; j >= 0; --j) {
        x = fmaf(c[j], x, d[j]);
        adv[j] = x;
    }
    const float mean = stats[0];
    const float inv  = stats[1];
    if (base + ITEMS <= n) {
        float l[ITEMS], o[ITEMS];
        const float4* l4 = (const float4*)(lp + base);
        const float4* o4 = (const float4*)(olp + base);
#pragma unroll
        for (int k = 0; k < 2; ++k) {
            float4 q = l4[k]; l[4*k]=q.x; l[4*k+1]=q.y; l[4*k+2]=q.z; l[4*k+3]=q.w;
            float4 w = o4[k]; o[4*k]=w.x; o[4*k+1]=w.y; o[4*k+2]=w.z; o[4*k+3]=w.w;
        }
        float buf[3 * ITEMS];
#pragma unroll
        for (int j = 0; j < ITEMS; ++j) {
            float an = (adv[j] - mean) * inv;
            float ratio = expf(l[j] - o[j]);
            float cl = fminf(fmaxf(ratio, 0.8f), 1.2f);
            buf[3*j]     = an;
            buf[3*j + 1] = adv[j] + v[j];
            buf[3*j + 2] = -fminf(ratio * an, cl * an);
        }
        float4* dst = (float4*)(out + 3 * base);   // 3*base % 4 == 0 → 16B aligned
#pragma unroll
        for (int k = 0; k < 6; ++k)
            dst[k] = make_float4(buf[4*k], buf[4*k+1], buf[4*k+2], buf[4*k+3]);
    } else {
        for (int j = 0; j < ITEMS; ++j) {
            long i = base + j;
            if (i < (long)n) {
                float an = (adv[j] - mean) * inv;
                float ratio = expf(lp[i] - olp[i]);
                float cl = fminf(fmaxf(ratio, 0.8f), 1.2f);
                out[3*i]     = an;
                out[3*i + 1] = adv[j] + v[j];
                out[3*i + 2] = -fminf(ratio * an, cl * an);
            }
        }
    }
}

extern "C" void kernel_launch(void* const* d_in, const int* in_sizes, int n_in,
                              void* d_out, int out_size, void* d_ws, size_t ws_size,
                              hipStream_t stream) {
    const float* rewards     = (const float*)d_in[0];
    const float* values      = (const float*)d_in[1];
    const float* next_values = (const float*)d_in[2];
    const float* lp          = (const float*)d_in[3];
    const float* olp         = (const float*)d_in[4];
    const void*  term        = d_in[5];
    const void*  trunc       = d_in[6];
    float* out = (float*)d_out;
    int n = in_sizes[0];
    int nb = (n + CHUNK - 1) / CHUNK;   // 1024 for N=2^21; must be <= MAXNB

    char* ws = (char*)d_ws;
    float2* blockAgg = (float2*)ws;                                   // 8 KB
    float4* bs4      = (float4*)(ws + MAXNB * 8);                     // 16 KB
    float*  bs1      = (float*) (ws + MAXNB * 8 + MAXNB * 16);        // 4 KB
    float*  S        = (float*) (ws + MAXNB * 8 + MAXNB * 16 + MAXNB * 4);
    float*  stats    = (float*) (ws + MAXNB * 8 + MAXNB * 16 + MAXNB * 8);
    float2* E2       = (float2*)(ws + MAXNB * 8 + MAXNB * 16 + MAXNB * 8 + 256); // 2 MB

    k1_agg <<<nb, BLOCK, 0, stream>>>(rewards, values, next_values, term, trunc,
                                      blockAgg, E2, bs4, bs1, n);
    k2_scan<<<1,  BLOCK, 0, stream>>>(blockAgg, bs4, bs1, S, stats, nb, n);
    k3_final<<<nb, BLOCK, 0, stream>>>(rewards, values, next_values, term, trunc,
                                       lp, olp, E2, S, stats, out, n);
}

// Round 8
// 130.131 us; speedup vs baseline: 1.8495x; 1.0028x over previous
//
#include <hip/hip_runtime.h>
#include <stdint.h>

static constexpr int BLOCK = 256;
static constexpr int ITEMS = 8;
static constexpr int CHUNK = BLOCK * ITEMS;   // 2048 elements per block
static constexpr int MAXNB = 1024;            // 1024 * 2048 = 2097152 = N

#define GAMMA_F 0.99f
static __device__ __forceinline__ float gl_const() { return (float)(0.99 * 0.95); }

// affine compose: self ∘ right (right applied first): x -> a1*(a2*x+b2)+b1
__device__ __forceinline__ void compose(float& a1, float& b1, float a2, float b2) {
    b1 = fmaf(a1, b2, b1);
    a1 = a1 * a2;
}

// ---------------- bool dtype runtime probe ----------------
// 0 = int32, 1 = uint8/bool, 2 = float32. Byte pattern of first 1024 bytes.
__device__ __forceinline__ int detect_mode(const void* term, int n_elems, int* flg) {
    int t = threadIdx.x;
    if (t == 0) { flg[0] = 0; flg[1] = 0; }
    __syncthreads();
    if (t < 256) {
        const unsigned char* p = (const unsigned char*)term;
        int i0 = 4 * t;
        if (i0 + 3 < n_elems) {
            unsigned b1 = p[i0 + 1], b2 = p[i0 + 2], b3 = p[i0 + 3];
            if (b1) atomicOr(&flg[0], 1);
            if (b2 | b3) atomicOr(&flg[1], 1);
        }
    }
    __syncthreads();
    return flg[0] ? 1 : (flg[1] ? 2 : 0);
}

__device__ __forceinline__ int load_bool1(const void* p, long i, int mode) {
    if (mode == 1) return ((const unsigned char*)p)[i] != 0;
    if (mode == 0) return ((const int*)p)[i] != 0;
    return ((const float*)p)[i] != 0.0f;
}

__device__ __forceinline__ void load_bool8(const void* p, long base, int mode, int* f) {
    if (mode == 1) {
        uint2 q = *(const uint2*)((const unsigned char*)p + base);
        unsigned w[2] = {q.x, q.y};
#pragma unroll
        for (int j = 0; j < 8; ++j) f[j] = (int)((w[j >> 2] >> ((j & 3) * 8)) & 0xffu);
    } else if (mode == 0) {
        const int4* q = (const int4*)((const int*)p + base);
#pragma unroll
        for (int k = 0; k < 2; ++k) {
            int4 v = q[k];
            f[4*k] = v.x; f[4*k+1] = v.y; f[4*k+2] = v.z; f[4*k+3] = v.w;
        }
    } else {
        const float4* q = (const float4*)((const float*)p + base);
#pragma unroll
        for (int k = 0; k < 2; ++k) {
            float4 v = q[k];
            f[4*k] = v.x != 0.f; f[4*k+1] = v.y != 0.f; f[4*k+2] = v.z != 0.f; f[4*k+3] = v.w != 0.f;
        }
    }
}

// c[j] = not_done * gamma*lambda ; d[j] = r + gamma*not_term*nv - v
__device__ __forceinline__ void compute_cd(
    const float* __restrict__ rewards, const float* __restrict__ values,
    const float* __restrict__ next_values, const void* __restrict__ term,
    const void* __restrict__ trunc, int mode, long base, int n,
    float* c, float* d, float* v)
{
    const float GL = gl_const();
    if (base + ITEMS <= n) {
        float r[ITEMS], nv[ITEMS];
        const float4* r4 = (const float4*)(rewards + base);
        const float4* v4 = (const float4*)(values + base);
        const float4* n4 = (const float4*)(next_values + base);
#pragma unroll
        for (int k = 0; k < 2; ++k) {
            float4 a = r4[k]; r[4*k]=a.x; r[4*k+1]=a.y; r[4*k+2]=a.z; r[4*k+3]=a.w;
            float4 b = v4[k]; v[4*k]=b.x; v[4*k+1]=b.y; v[4*k+2]=b.z; v[4*k+3]=b.w;
            float4 q = n4[k]; nv[4*k]=q.x; nv[4*k+1]=q.y; nv[4*k+2]=q.z; nv[4*k+3]=q.w;
        }
        int tm[ITEMS], tr[ITEMS];
        load_bool8(term,  base, mode, tm);
        load_bool8(trunc, base, mode, tr);
#pragma unroll
        for (int j = 0; j < ITEMS; ++j) {
            float nt = tm[j] ? 0.f : 1.f;
            float nd = (tm[j] | tr[j]) ? 0.f : 1.f;
            d[j] = r[j] + GAMMA_F * nt * nv[j] - v[j];
            c[j] = nd * GL;
        }
    } else {
#pragma unroll
        for (int j = 0; j < ITEMS; ++j) {
            long i = base + j;
            if (i < (long)n) {
                int tm = load_bool1(term, i, mode);
                int tr = load_bool1(trunc, i, mode);
                float nt = tm ? 0.f : 1.f;
                float nd = (tm | tr) ? 0.f : 1.f;
                v[j] = values[i];
                d[j] = rewards[i] + GAMMA_F * nt * next_values[i] - v[j];
                c[j] = nd * GL;
            } else { c[j] = 1.f; d[j] = 0.f; v[j] = 0.f; }
        }
    }
}

// ---------------- K1: shuffle-scan aggregates + entry maps + moment scalars ----
// NO device atomics / elections (round-5 lesson: ~1000 serialized same-address
// device atomics ≈ 100 µs on MI355X — a separate 2 µs launch is 50x cheaper).
__global__ __launch_bounds__(BLOCK) void k1_agg(
    const float* __restrict__ rewards, const float* __restrict__ values,
    const float* __restrict__ next_values, const void* __restrict__ term,
    const void* __restrict__ trunc, float2* __restrict__ blockAgg,
    float2* __restrict__ E2, float4* __restrict__ bs4, float* __restrict__ bs1,
    int n)
{
    __shared__ int flg[2];
    __shared__ float wA[4], wB[4];
    __shared__ float red[4][5];

    const int t = threadIdx.x;
    const int lane = t & 63, w = t >> 6;
    const int bid = blockIdx.x;
    const int mode = detect_mode(term, n, flg);
    const long base = (long)bid * CHUNK + (long)t * ITEMS;

    float c[ITEMS], d[ITEMS], v[ITEMS];
    compute_cd(rewards, values, next_values, term, trunc, mode, base, n, c, d, v);

    // thread-serial affine aggregate of this thread's 8 items
    float a = 1.f, b = 0.f;
#pragma unroll
    for (int j = ITEMS - 1; j >= 0; --j) { b = fmaf(c[j], b, d[j]); a *= c[j]; }

    // wave suffix-inclusive scan via shuffles: H_l = F_l ∘ ... ∘ F_63
#pragma unroll
    for (int dd = 1; dd < 64; dd <<= 1) {
        float ra = __shfl_down(a, dd, 64);
        float rb = __shfl_down(b, dd, 64);
        if (lane + dd < 64) { b = fmaf(a, rb, b); a *= ra; }
    }
    if (lane == 0) { wA[w] = a; wB[w] = b; }   // wave aggregate
    // within-wave exclusive entry E = H_{l+1} (identity at lane 63)
    float ea = __shfl_down(a, 1, 64);
    float eb = __shfl_down(b, 1, 64);
    if (lane == 63) { ea = 1.f; eb = 0.f; }
    __syncthreads();
    // compose with later-wave aggregates
    for (int ww = w + 1; ww < 4; ++ww) compose(ea, eb, wA[ww], wB[ww]);
    if (t == 0) {
        float Aa = wA[0], Ab = wB[0];
        for (int ww = 1; ww < 4; ++ww) compose(Aa, Ab, wA[ww], wB[ww]);
        blockAgg[bid] = make_float2(Aa, Ab);
    }
    // persist per-thread block-entry map for the finalize kernel
    E2[(long)bid * BLOCK + t] = make_float2(ea, eb);

    // symbolic replay: adv_j = p*x_b + q ; accumulate 5 moment scalars
    float p = ea, q = eb;
    float sP = 0.f, sQ = 0.f, sP2 = 0.f, sPQ = 0.f, sQ2 = 0.f;
#pragma unroll
    for (int j = ITEMS - 1; j >= 0; --j) {
        p = c[j] * p;
        q = fmaf(c[j], q, d[j]);
        if (base + j < (long)n) {
            sP += p; sQ += q; sP2 += p*p; sPQ += p*q; sQ2 += q*q;
        }
    }
#pragma unroll
    for (int dd = 32; dd > 0; dd >>= 1) {
        sP  += __shfl_down(sP,  dd, 64);
        sQ  += __shfl_down(sQ,  dd, 64);
        sP2 += __shfl_down(sP2, dd, 64);
        sPQ += __shfl_down(sPQ, dd, 64);
        sQ2 += __shfl_down(sQ2, dd, 64);
    }
    if (lane == 0) { red[w][0]=sP; red[w][1]=sQ; red[w][2]=sP2; red[w][3]=sPQ; red[w][4]=sQ2; }
    __syncthreads();
    if (t == 0) {
        float m0=0,m1=0,m2=0,m3=0,m4=0;
        for (int ww = 0; ww < 4; ++ww) { m0+=red[ww][0]; m1+=red[ww][1]; m2+=red[ww][2]; m3+=red[ww][3]; m4+=red[ww][4]; }
        bs4[bid] = make_float4(m0, m1, m2, m3);
        bs1[bid] = m4;
    }
}

// ---------------- K3: finalize; every block redundantly derives S[bid]+stats ----
// Replaces the 1-block K2 dispatch: each block scans the nb (<=1024) aggregates
// in LDS (~28 KB of L2-broadcast reads) — redundant compute beats an extra
// dispatch + gap, with no atomics (round-5 lesson).
__global__ __launch_bounds__(BLOCK) void k3_final(
    const float* __restrict__ rewards, const float* __restrict__ values,
    const float* __restrict__ next_values, const void* __restrict__ term,
    const void* __restrict__ trunc, const float* __restrict__ lp,
    const float* __restrict__ olp, const float2* __restrict__ E2,
    const float2* __restrict__ blockAgg, const float4* __restrict__ bs4,
    const float* __restrict__ bs1, float* __restrict__ out, int n, int nb)
{
    __shared__ int flg[2];
    __shared__ float sA[BLOCK], sB[BLOCK];
    __shared__ float sS[MAXNB];
    __shared__ double dS[BLOCK], dS2[BLOCK];
    __shared__ float statMean, statInv;

    const int t = threadIdx.x;
    const int bid = blockIdx.x;
    const int mode = detect_mode(term, n, flg);
    const long base = (long)bid * CHUNK + (long)t * ITEMS;

    // issue the streaming loads first — the aggregate scan below overlaps them
    float c[ITEMS], d[ITEMS], v[ITEMS];
    compute_cd(rewards, values, next_values, term, trunc, mode, base, n, c, d, v);
    float2 e = E2[(long)bid * BLOCK + t];

    // ---- redundant per-block suffix scan of nb aggregates + stats (ex-K2) ----
    float la[4], lb[4];
#pragma unroll
    for (int j = 0; j < 4; ++j) {
        int i = 4 * t + j;
        if (i < nb) { float2 f = blockAgg[i]; la[j] = f.x; lb[j] = f.y; }
        else        { la[j] = 1.f; lb[j] = 0.f; }
    }
    float a = 1.f, b = 0.f;
#pragma unroll
    for (int j = 3; j >= 0; --j) { b = fmaf(la[j], b, lb[j]); a *= la[j]; }
    sA[t] = a; sB[t] = b;
    __syncthreads();
    for (int dd = 1; dd < BLOCK; dd <<= 1) {
        float ra = 1.f, rb = 0.f;
        if (t + dd < BLOCK) { ra = sA[t + dd]; rb = sB[t + dd]; }
        __syncthreads();
        b = fmaf(a, rb, b);
        a *= ra;
        sA[t] = a; sB[t] = b;
        __syncthreads();
    }
    float x = (t + 1 < BLOCK) ? sB[t + 1] : 0.f;   // suffix entering block 4t+3
    double ds = 0.0, ds2 = 0.0;
#pragma unroll
    for (int j = 3; j >= 0; --j) {
        int i = 4 * t + j;
        if (i < nb) {
            sS[i] = x;
            float4 s4 = bs4[i];
            double xd = (double)x;
            ds  += (double)s4.x * xd + (double)s4.y;
            ds2 += (double)s4.z * xd * xd + 2.0 * (double)s4.w * xd + (double)bs1[i];
        }
        x = fmaf(la[j], x, lb[j]);
    }
    dS[t] = ds; dS2[t] = ds2;
    __syncthreads();
    for (int dd = BLOCK / 2; dd > 0; dd >>= 1) {
        if (t < dd) { dS[t] += dS[t + dd]; dS2[t] += dS2[t + dd]; }
        __syncthreads();
    }
    if (t == 0) {
        double sum = dS[0], sumsq = dS2[0];
        double mean = sum / (double)n;
        double var = (sumsq - sum * sum / (double)n) / (double)(n - 1);
        if (var < 0.0) var = 0.0;
        statMean = (float)mean;
        statInv  = 1.0f / ((float)sqrt(var) + 1e-9f);
    }
    __syncthreads();

    // ---- replay + finalize ----
    float xx = fmaf(e.x, sS[bid], e.y);
    float adv[ITEMS];
#pragma unroll
    for (int j = ITEMS - 1; j >= 0; --j) {
        xx = fmaf(c[j], xx, d[j]);
        adv[j] = xx;
    }
    const float mean = statMean;
    const float inv  = statInv;
    if (base + ITEMS <= n) {
        float l[ITEMS], o[ITEMS];
        const float4* l4 = (const float4*)(lp + base);
        const float4* o4 = (const float4*)(olp + base);
#pragma unroll
        for (int k = 0; k < 2; ++k) {
            float4 q = l4[k]; l[4*k]=q.x; l[4*k+1]=q.y; l[4*k+2]=q.z; l[4*k+3]=q.w;
            float4 w = o4[k]; o[4*k]=w.x; o[4*k+1]=w.y; o[4*k+2]=w.z; o[4*k+3]=w.w;
        }
        float buf[3 * ITEMS];
#pragma unroll
        for (int j = 0; j < ITEMS; ++j) {
            float an = (adv[j] - mean) * inv;
            float ratio = expf(l[j] - o[j]);
            float cl = fminf(fmaxf(ratio, 0.8f), 1.2f);
            buf[3*j]     = an;
            buf[3*j + 1] = adv[j] + v[j];
            buf[3*j + 2] = -fminf(ratio * an, cl * an);
        }
        float4* dst = (float4*)(out + 3 * base);   // 3*base % 4 == 0 → 16B aligned
#pragma unroll
        for (int k = 0; k < 6; ++k)
            dst[k] = make_float4(buf[4*k], buf[4*k+1], buf[4*k+2], buf[4*k+3]);
    } else {
        for (int j = 0; j < ITEMS; ++j) {
            long i = base + j;
            if (i < (long)n) {
                float an = (adv[j] - mean) * inv;
                float ratio = expf(lp[i] - olp[i]);
                float cl = fminf(fmaxf(ratio, 0.8f), 1.2f);
                out[3*i]     = an;
                out[3*i + 1] = adv[j] + v[j];
                out[3*i + 2] = -fminf(ratio * an, cl * an);
            }
        }
    }
}

extern "C" void kernel_launch(void* const* d_in, const int* in_sizes, int n_in,
                              void* d_out, int out_size, void* d_ws, size_t ws_size,
                              hipStream_t stream) {
    const float* rewards     = (const float*)d_in[0];
    const float* values      = (const float*)d_in[1];
    const float* next_values = (const float*)d_in[2];
    const float* lp          = (const float*)d_in[3];
    const float* olp         = (const float*)d_in[4];
    const void*  term        = d_in[5];
    const void*  trunc       = d_in[6];
    float* out = (float*)d_out;
    int n = in_sizes[0];
    int nb = (n + CHUNK - 1) / CHUNK;   // 1024 for N=2^21; must be <= MAXNB

    char* ws = (char*)d_ws;
    float2* blockAgg = (float2*)ws;                                   // 8 KB
    float4* bs4      = (float4*)(ws + MAXNB * 8);                     // 16 KB
    float*  bs1      = (float*) (ws + MAXNB * 8 + MAXNB * 16);        // 4 KB
    float2* E2       = (float2*)(ws + MAXNB * 8 + MAXNB * 16 + MAXNB * 4 + 256); // 2 MB

    k1_agg <<<nb, BLOCK, 0, stream>>>(rewards, values, next_values, term, trunc,
                                      blockAgg, E2, bs4, bs1, n);
    k3_final<<<nb, BLOCK, 0, stream>>>(rewards, values, next_values, term, trunc,
                                       lp, olp, E2, blockAgg, bs4, bs1, out, n, nb);
}